// Round 22
// baseline (202.025 us; speedup 1.0000x reference)
//
#include <hip/hip_runtime.h>

#define BB 128
#define TT 224
#define LL 224

typedef float v2f __attribute__((ext_vector_type(2)));

__device__ __forceinline__ float rcpf(float x){ return __builtin_amdgcn_rcpf(x); }

#if __has_builtin(__builtin_amdgcn_exp2f)
#define EXP2(x) __builtin_amdgcn_exp2f(x)
#else
#define EXP2(x) __expf((x)*0.6931471805599453f)
#endif

// DPP row rotate-right by N: dst[k] = src[(k-N)&15] within each 16-lane row
template<int N>
__device__ __forceinline__ float rorN(float x){
  int xi = __builtin_bit_cast(int, x);
  xi = __builtin_amdgcn_update_dpp(xi, xi, 0x120 + N, 0xf, 0xf, false);
  return __builtin_bit_cast(float, xi);
}

// v_permlane32_swap_b32: with a==b==x -> a'=low-half bcast, b'=high-half bcast
__device__ __forceinline__ void swap32(float& a, float& b){
  asm volatile("s_nop 1\n\tv_permlane32_swap_b32 %0, %1\n\ts_nop 1"
               : "+v"(a), "+v"(b));
}

// ---- K1: conv chain + layer-1 pre-gate + Wtb precompute ------------------
// blocks [0,36): Wtb[o][n] = fcw3 @ fcw2 (coalesced over n).
// blocks [36, 36+1792): 32 rows per block (all blocks co-resident, single
// scheduling round): register-direct conv + pool + pregate.
__global__ __launch_bounds__(256) void convpre_kernel(const float* __restrict__ x,
    const float* __restrict__ c1w1, const float* __restrict__ c1b1,
    const float* __restrict__ c1w2, const float* __restrict__ c1b2,
    const float* __restrict__ c2w1, const float* __restrict__ c2b1,
    const float* __restrict__ c2w2, const float* __restrict__ c2b2,
    const float* __restrict__ l10Wih, const float* __restrict__ l10b,
    const float* __restrict__ l20Wih, const float* __restrict__ l20b,
    float* __restrict__ pre,
    const float* __restrict__ fcw2, const float* __restrict__ fcw3,
    float* __restrict__ Wtb)
{
  __shared__ float sb[2848];
  int gb  = blockIdx.x;
  int tid = threadIdx.x;

  if (gb < 36){
    int idx = gb*256 + tid;       // < 9216
    int o = idx >> 10, n = idx & 1023;
    float acc = 0.f;
    for (int p=0;p<192;p++) acc += fcw3[o*192+p]*fcw2[(size_t)p*1024+n];
    Wtb[idx] = acc;
    return;
  }

  // -------- conv + pregate path: 32 rows per block --------
  float* c1s  = sb;          // row*57 + cj   (32*57 = 1824)
  float* y4   = sb + 1824;   // row*32 + j    (32*32 = 1024, b128-aligned)

  int blk = gb - 36;                  // 0..1791
  int branch = (blk >= 896);
  int lblk = blk - branch*896;
  int b  = lblk / 7;
  int t0 = (lblk - b*7)*32;
  size_t rbase = ((size_t)(branch*128 + b))*224 + t0;   // global x row
  size_t prow  = (size_t)b*224 + t0;                    // pre row within run

  const float* w1 = branch ? c2w1 : c1w1;
  const float* w2 = branch ? c2w2 : c1w2;
  float b1  = branch ? c2b1[0] : c1b1[0];
  float b2v = branch ? c2b2[0] : c1b2[0];
  const float* wih = branch ? l20Wih : l10Wih;   // (2,48,28)
  const float* bia = branch ? l20b   : l10b;     // (2,48)

  // conv1 stride-4 pad-2 + relu, register-direct: 1 thread per (row, oct)
  // 224 threads = 32 rows x 7 groups of 8 outputs
  if (tid < 224){
    int row  = tid / 7, grp = tid - row*7;
    int cj0  = grp*8;
    int bx   = 4*cj0 - 4;
    const float* xrow = x + (rbase + row)*224;
    float w1r[8];
    #pragma unroll
    for (int kk=0;kk<8;kk++) w1r[kk]=w1[kk];
    float xr[40];
    #pragma unroll
    for (int q=0;q<10;q++){
      int idx = bx + 4*q;
      if (idx >= 0 && idx <= 220){
        float4 v = *(const float4*)(xrow + idx);
        xr[4*q]=v.x; xr[4*q+1]=v.y; xr[4*q+2]=v.z; xr[4*q+3]=v.w;
      } else {
        #pragma unroll
        for (int e=0;e<4;e++){
          int ii = idx+e;
          xr[4*q+e] = (ii>=0 && ii<224) ? xrow[ii] : 0.f;
        }
      }
    }
    #pragma unroll
    for (int e=0;e<8;e++){
      float s = b1;
      #pragma unroll
      for (int kk=0;kk<8;kk++) s += xr[4*e+2+kk]*w1r[kk];
      c1s[row*57 + cj0 + e] = fmaxf(s, 0.f);
    }
  }
  __syncthreads();

  // maxpool(4,2,pad1) + relu + conv3(pad1) + relu : 32 rows x 28 j = 896
  for (int i = tid; i < 896; i += 256){
    int row = i / 28, j = i - row*28;
    const float* cr = &c1s[row*57];
    float o = b2v;
    #pragma unroll
    for (int pi=0;pi<3;pi++){
      int p = j - 1 + pi;
      float pool = 0.f;
      if (p>=0 && p<28){
        int i0 = 2*p - 1;
        float m = -1e30f;
        #pragma unroll
        for (int q=0;q<4;q++){
          int ii = i0+q;
          if (ii>=0 && ii<56) m = fmaxf(m, cr[ii]);
        }
        pool = fmaxf(m, 0.f);
      }
      o += pool * w2[pi];
    }
    y4[row*32 + j] = fmaxf(o, 0.f);
  }
  __syncthreads();

  // pregate: 192 threads; weights cached in 7 f4 regs; 16 rows each
  if (tid < 192){
    int d   = tid / 96;
    int g96 = tid - d*96;
    int row = g96 % 48;
    int rrg = g96 / 48;
    const float4* wr = (const float4*)(wih + (d*48 + row)*28);  // 112B-aligned
    float4 wv[7];
    #pragma unroll
    for (int q=0;q<7;q++) wv[q] = wr[q];
    float bias = bia[d*48 + row];
    int unit = row % 12, g = row / 12;
    float* prebase = pre + (size_t)(2*branch + d)*(TT*BB*48) + unit*4 + g;
    #pragma unroll
    for (int rq=0; rq<16; rq++){
      int rr = rrg*16 + rq;
      const float4* yv = (const float4*)&y4[rr*32];
      float acc = bias;
      #pragma unroll
      for (int q=0;q<7;q++){
        float4 yq = yv[q];
        acc += yq.x*wv[q].x + yq.y*wv[q].y + yq.z*wv[q].z + yq.w*wv[q].w;
      }
      prebase[(prow + rr)*48] = acc;
    }
  }
}

// ---------------- K3: LSTM scan + light shadow-FC blocks ------------------
// blocks [0,256): lstm single-chain (R11 form).
// phase 0 shadow (layer-1): wpartA-64 (load Wt tile from Wtb, split-K) +
//   BCpart emit.  phase 1 shadow (layer-2): wpartB (Wc reduce) + BC final.
#define LSTM_STEP(P, SS) { \
  float x1=rorN<1>(hv), x2=rorN<2>(hv), x3=rorN<3>(hv), x4=rorN<4>(hv), \
        x5=rorN<5>(hv), x6=rorN<6>(hv), x7=rorN<7>(hv), x8=rorN<8>(hv), \
        x9=rorN<9>(hv), x10=rorN<10>(hv), x11=rorN<11>(hv), x12=rorN<12>(hv), \
        x13=rorN<13>(hv), x14=rorN<14>(hv), x15=rorN<15>(hv); \
  v2f a0 = (P); \
  a0 += w[0]*(v2f){hv,hv};   a0 += w[1]*(v2f){x1,x1};   a0 += w[2]*(v2f){x2,x2};   a0 += w[3]*(v2f){x3,x3}; \
  v2f a1 = w[4]*(v2f){x4,x4};   a1 += w[5]*(v2f){x5,x5};   a1 += w[6]*(v2f){x6,x6};   a1 += w[7]*(v2f){x7,x7}; \
  v2f a2 = w[8]*(v2f){x8,x8};   a2 += w[9]*(v2f){x9,x9};   a2 += w[10]*(v2f){x10,x10}; a2 += w[11]*(v2f){x11,x11}; \
  v2f a3 = w[12]*(v2f){x12,x12}; a3 += w[13]*(v2f){x13,x13}; a3 += w[14]*(v2f){x14,x14}; a3 += w[15]*(v2f){x15,x15}; \
  v2f gg = (a0+a1)+(a2+a3); \
  v2f m  = gg*kmul; \
  v2f e  = { EXP2(m.x), EXP2(m.y) }; \
  e += (v2f){1.f,1.f}; \
  v2f d  = { rcpf(e.x), rcpf(e.y) }; \
  v2f res = ca*d + cb; \
  float p0 = res.x, p1 = res.x; swap32(p0, p1); \
  float q0 = res.y, q1 = res.y; swap32(q0, q1); \
  cst = fmaf(q0, cst, p0*p1); \
  float et = EXP2(cst*2.885390082f); \
  float dt = rcpf(et+1.f); \
  hv = q1*fmaf(-2.f, dt, 1.f); \
  hbuf[SS] = hv; }

#define FLUSH8 { \
  if (doSt){ \
    _Pragma("unroll") \
    for (int q=0;q<8;q++) outP[q*ostep] = hbuf[q]; \
  } \
  outP += 8*ostep; }

__global__ __launch_bounds__(64) __attribute__((amdgpu_waves_per_eu(1,1)))
void lstm_kernel(const float* __restrict__ pre,
    const float* __restrict__ whhA, const float* __restrict__ whhB,
    float* __restrict__ out,
    const float* __restrict__ fcw1, const float* __restrict__ fcb1,
    const float* __restrict__ Wtb,
    float* __restrict__ wpart, float* __restrict__ BCpart,
    const float* __restrict__ fcw3, const float* __restrict__ fcb2,
    const float* __restrict__ fcb3, float* __restrict__ Wc,
    float* __restrict__ BC, int phase)
{
  __shared__ float wt[576];
  int blk  = blockIdx.x;
  int lane = threadIdx.x;

  if (blk >= 256){
    int xb  = blk - 256;
    if (phase == 0){
      // ---- shadow wpartA-64: load Wt tile, split-K over fcw1 ----
      int s   = xb / 84;            // K-chunk 0..15
      int j64 = xb % 84;            // 64-wide j group
      #pragma unroll
      for (int q=0;q<9;q++) wt[q*64+lane] = Wtb[q*1024 + s*64 + lane];
      __syncthreads();
      int j = j64*64 + lane;
      int nbase = s*64;
      float acc[9];
      #pragma unroll
      for (int o=0;o<9;o++) acc[o]=0.f;
      #pragma unroll 4
      for (int n4=0;n4<16;n4++){
        int nb = nbase + n4*4;
        float4 v4;
        v4.x = fcw1[(size_t)(nb  )*5376 + j];
        v4.y = fcw1[(size_t)(nb+1)*5376 + j];
        v4.z = fcw1[(size_t)(nb+2)*5376 + j];
        v4.w = fcw1[(size_t)(nb+3)*5376 + j];
        #pragma unroll
        for (int o=0;o<9;o++){
          float4 w4 = *(const float4*)&wt[o*64 + n4*4];
          acc[o] += v4.x*w4.x + v4.y*w4.y + v4.z*w4.z + v4.w*w4.w;
        }
      }
      #pragma unroll
      for (int o=0;o<9;o++) wpart[((size_t)s*9+o)*5376 + j] = acc[o];
      if (j64 == 0 && lane < 9){
        float bcp = 0.f;
        for (int n=0;n<64;n++) bcp += wt[lane*64+n]*fcb1[nbase+n];
        BCpart[s*9+lane] = bcp;
      }
    } else {
      if (xb < 189){
        // wpartB: Wc = sum_s wpart[s]; 4 elems per lane
        #pragma unroll
        for (int q=0;q<4;q++){
          int idx = xb*256 + q*64 + lane;
          float a = 0.f;
          #pragma unroll
          for (int s=0;s<16;s++) a += wpart[(size_t)s*48384 + idx];
          Wc[idx] = a;
        }
      } else if (lane < 9){
        float acc = fcb3[lane];
        const float* f3 = fcw3 + lane*192;
        for (int p=0;p<192;p++) acc += f3[p]*fcb2[p];
        #pragma unroll
        for (int s=0;s<16;s++) acc += BCpart[s*9+lane];
        BC[lane] = acc;
      }
    }
    return;
  }

  // ---- lstm chain ----
  int r    = blk >> 6;            // run 0..3 (64 blocks per run)
  int br   = r >> 1, dir = r & 1;
  int u    = lane & 15;
  int bh   = (lane >> 4) & 1;
  int rbit = lane >> 5;
  int keff = (u < 12) ? u : 11;
  int b    = (blk & 63)*2 + bh;
  const float* whh = (br ? whhB : whhA) + dir*48*12;

  v2f w[16];
  #pragma unroll
  for (int rr=0; rr<16; rr++){
    int j = (u - rr) & 15;
    bool vld = (j < 12) && (u < 12);
    int uw = (u < 12) ? u : 0;
    int jw = (j < 12) ? j : 0;
    float wa = whh[((rbit?24:0)  + uw)*12 + jw];
    float wb = whh[((rbit?36:12) + uw)*12 + jw];
    w[rr] = (v2f){ vld ? wa : 0.f, vld ? wb : 0.f };
  }
  const v2f kmul = rbit ? (v2f){2.885390082f, -1.442695041f}
                        : (v2f){-1.442695041f, -1.442695041f};
  const v2f ca   = rbit ? (v2f){-2.f, 1.f} : (v2f){1.f, 1.f};
  const v2f cb   = rbit ? (v2f){ 1.f, 0.f} : (v2f){0.f, 0.f};

  const float* preR = pre + (size_t)r*(TT*BB*48) + (size_t)b*(TT*48) + keff*4 + rbit*2;
  const int sstep = dir ? -48 : 48;
  int scb = dir ? 223*48 : 0;

  v2f pcur[8], pnext[8];
  #pragma unroll
  for (int i=0;i<8;i++) pcur[i]  = *(const v2f*)(preR + scb +  i   *sstep);
  #pragma unroll
  for (int i=0;i<8;i++) pnext[i] = *(const v2f*)(preR + scb + (i+8)*sstep);
  int lb = scb + 16*sstep;

  float hv = 0.f, cst = 0.f;
  float hbuf[8];
  const int ostep = dir ? -24 : 24;
  float* outP = out + (size_t)br*(BB*TT*24) + (size_t)b*TT*24 + dir*12 + u
              + (size_t)(dir ? 223 : 0)*24;
  const bool doSt = (rbit==0) && (u < 12);

  for (int c=0;c<14;c++){
    LSTM_STEP(pcur[0],0) LSTM_STEP(pcur[1],1) LSTM_STEP(pcur[2],2) LSTM_STEP(pcur[3],3)
    LSTM_STEP(pcur[4],4) LSTM_STEP(pcur[5],5) LSTM_STEP(pcur[6],6) LSTM_STEP(pcur[7],7)
    FLUSH8
    if (c < 13){
      #pragma unroll
      for (int i=0;i<8;i++) pcur[i] = *(const v2f*)(preR + lb + i*sstep);
      lb += 8*sstep;
    }
    LSTM_STEP(pnext[0],0) LSTM_STEP(pnext[1],1) LSTM_STEP(pnext[2],2) LSTM_STEP(pnext[3],3)
    LSTM_STEP(pnext[4],4) LSTM_STEP(pnext[5],5) LSTM_STEP(pnext[6],6) LSTM_STEP(pnext[7],7)
    FLUSH8
    if (c < 13){
      #pragma unroll
      for (int i=0;i<8;i++) pnext[i] = *(const v2f*)(preR + lb + i*sstep);
      lb += 8*sstep;
    }
  }
}

// -------- K2: layer-2 pre-gate GEMM (pure) -------------------------------
__global__ __launch_bounds__(256) void pregate2_kernel(
    const float* __restrict__ in,
    const float* __restrict__ wihA, const float* __restrict__ biasA,
    const float* __restrict__ wihB, const float* __restrict__ biasB,
    float* __restrict__ pre)
{
  const int D = 24;
  __shared__ float sb[48*24 + 48];
  int gb  = blockIdx.x;
  int tid = threadIdx.x;

  float* wL = sb;
  float* bL = sb + 48*D;
  int r = gb / 1344;
  int lin = (gb % 1344)*256 + tid;
  int br = r>>1, dir = r&1;
  const float* wih  = (br ? wihB  : wihA)  + dir*48*D;
  const float* bias = (br ? biasB : biasA) + dir*48;
  for (int i = tid; i < 48*D; i += 256) wL[i]=wih[i];
  if (tid < 48) bL[tid]=bias[tid];
  __syncthreads();
  int tb = lin/12;  int k = lin - tb*12;   // tb = b*224 + t (batch-major)
  const float* rowp = in + (size_t)br*688128 + (size_t)tb*D;
  float aI=bL[k], aF=bL[12+k], aG=bL[24+k], aO=bL[36+k];
  const float4* rp4 = (const float4*)rowp;
  #pragma unroll
  for (int d4=0; d4<D/4; d4++){
    float4 xv = rp4[d4];
    float4 wI = *(const float4*)&wL[(0*12+k)*D + d4*4];
    float4 wF = *(const float4*)&wL[(1*12+k)*D + d4*4];
    float4 wG = *(const float4*)&wL[(2*12+k)*D + d4*4];
    float4 wO = *(const float4*)&wL[(3*12+k)*D + d4*4];
    aI += xv.x*wI.x + xv.y*wI.y + xv.z*wI.z + xv.w*wI.w;
    aF += xv.x*wF.x + xv.y*wF.y + xv.z*wF.z + xv.w*wF.w;
    aG += xv.x*wG.x + xv.y*wG.y + xv.z*wG.z + xv.w*wG.w;
    aO += xv.x*wO.x + xv.y*wO.y + xv.z*wO.z + xv.w*wO.w;
  }
  float4* o = (float4*)(pre + (size_t)r*(TT*BB*48) + (size_t)tb*48 + k*4);
  *o = make_float4(aI,aF,aG,aO);
}

// ---------------- K6c: out[m][o] = (w1*o1+w2*o2) . Wc[o] + BC[o] ----------
__global__ void final_kernel(const float* __restrict__ o1, const float* __restrict__ o2,
    const float* __restrict__ Wc, const float* __restrict__ BC,
    const float* __restrict__ w1p, const float* __restrict__ w2p,
    float* __restrict__ out)
{
  int wid  = blockIdx.x*4 + (threadIdx.x>>6);
  int lane = threadIdx.x & 63;
  if (wid >= 128*9) return;
  int m = wid / 9, o = wid - m*9;
  float w1 = w1p[0], w2 = w2p[0];
  const float* r1 = o1 + (size_t)m*5376;
  const float* r2 = o2 + (size_t)m*5376;
  const float* wc = Wc + (size_t)o*5376;
  float acc = 0.f;
  for (int i=lane;i<5376;i+=64){
    acc += (w1*r1[i] + w2*r2[i]) * wc[i];
  }
  #pragma unroll
  for (int off=32;off;off>>=1) acc += __shfl_down(acc, off);
  if (lane==0) out[m*9+o] = acc + BC[o];
}

extern "C" void kernel_launch(void* const* d_in, const int* in_sizes, int n_in,
                              void* d_out, int out_size, void* d_ws, size_t ws_size,
                              hipStream_t stream) {
  (void)in_sizes; (void)n_in; (void)out_size; (void)ws_size;
  const float* x    = (const float*)d_in[0];
  const float* c1w1 = (const float*)d_in[1];
  const float* c1b1 = (const float*)d_in[2];
  const float* c1w2 = (const float*)d_in[3];
  const float* c1b2 = (const float*)d_in[4];
  const float* c2w1 = (const float*)d_in[5];
  const float* c2b1 = (const float*)d_in[6];
  const float* c2w2 = (const float*)d_in[7];
  const float* c2b2 = (const float*)d_in[8];
  const float* l10Wih = (const float*)d_in[9];
  const float* l10Whh = (const float*)d_in[10];
  const float* l10b   = (const float*)d_in[11];
  const float* l11Wih = (const float*)d_in[12];
  const float* l11Whh = (const float*)d_in[13];
  const float* l11b   = (const float*)d_in[14];
  const float* l20Wih = (const float*)d_in[15];
  const float* l20Whh = (const float*)d_in[16];
  const float* l20b   = (const float*)d_in[17];
  const float* l21Wih = (const float*)d_in[18];
  const float* l21Whh = (const float*)d_in[19];
  const float* l21b   = (const float*)d_in[20];
  const float* fcw1 = (const float*)d_in[21];
  const float* fcb1 = (const float*)d_in[22];
  const float* fcw2 = (const float*)d_in[23];
  const float* fcb2 = (const float*)d_in[24];
  const float* fcw3 = (const float*)d_in[25];
  const float* fcb3 = (const float*)d_in[26];
  const float* w1   = (const float*)d_in[27];
  const float* w2   = (const float*)d_in[28];
  float* out = (float*)d_out;

  float* ws  = (float*)d_ws;
  float* wpart = ws;                      // 774144
  float* pre  = ws  + 2*802816;           // 4 * 1376256
  float* ol0  = pre + 4*1376256;          // 2 * 688128
  float* ol1  = ol0 + 2*688128;           // 2 * 688128
  float* Wc   = ol1 + 2*688128;           // 48384
  float* BC   = Wc  + 48384;              // 9
  float* BCpart = BC + 9;                 // 144
  float* Wtb  = BCpart + 144;             // 9216

  convpre_kernel<<<1828,256,0,stream>>>(x, c1w1,c1b1,c1w2,c1b2, c2w1,c2b1,c2w2,c2b2,
      l10Wih, l10b, l20Wih, l20b, pre, fcw2, fcw3, Wtb);
  lstm_kernel<<<1600,64,0,stream>>>(pre, l10Whh, l20Whh, ol0,
      fcw1, fcb1, Wtb, wpart, BCpart, fcw3, fcb2, fcb3, Wc, BC, 0);
  pregate2_kernel<<<5376,256,0,stream>>>(ol0, l11Wih, l11b, l21Wih, l21b, pre);
  lstm_kernel<<<446,64,0,stream>>>(pre, l11Whh, l21Whh, ol1,
      fcw1, fcb1, Wtb, wpart, BCpart, fcw3, fcb2, fcb3, Wc, BC, 1);
  final_kernel<<<288,256,0,stream>>>(ol1, ol1+688128, Wc, BC, w1, w2, out);
}

// Round 23
// 163.574 us; speedup vs baseline: 1.2351x; 1.2351x over previous
//
#include <hip/hip_runtime.h>

#define BB 128
#define TT 224
#define LL 224

typedef float v2f __attribute__((ext_vector_type(2)));

__device__ __forceinline__ float rcpf(float x){ return __builtin_amdgcn_rcpf(x); }

#if __has_builtin(__builtin_amdgcn_exp2f)
#define EXP2(x) __builtin_amdgcn_exp2f(x)
#else
#define EXP2(x) __expf((x)*0.6931471805599453f)
#endif

// DPP row rotate-right by N: dst[k] = src[(k-N)&15] within each 16-lane row
template<int N>
__device__ __forceinline__ float rorN(float x){
  int xi = __builtin_bit_cast(int, x);
  xi = __builtin_amdgcn_update_dpp(xi, xi, 0x120 + N, 0xf, 0xf, false);
  return __builtin_bit_cast(float, xi);
}

// v_permlane32_swap_b32: with a==b==x -> a'=low-half bcast, b'=high-half bcast
__device__ __forceinline__ void swap32(float& a, float& b){
  asm volatile("s_nop 1\n\tv_permlane32_swap_b32 %0, %1\n\ts_nop 1"
               : "+v"(a), "+v"(b));
}

// ---- K1: conv chain + layer-1 pre-gate + Wtb precompute ------------------
// blocks [0,36): Wtb[o][n] = fcw3 @ fcw2 (coalesced over n).
// blocks [36, 36+3584): register-direct conv (16 rows) + pool + pregate
// (192 threads, weights cached in 7 f4 regs, y via b128 LDS reads).
// [R21-measured form: VGPR=36, FETCH~39MB, ~35us]
__global__ __launch_bounds__(256) void convpre_kernel(const float* __restrict__ x,
    const float* __restrict__ c1w1, const float* __restrict__ c1b1,
    const float* __restrict__ c1w2, const float* __restrict__ c1b2,
    const float* __restrict__ c2w1, const float* __restrict__ c2b1,
    const float* __restrict__ c2w2, const float* __restrict__ c2b2,
    const float* __restrict__ l10Wih, const float* __restrict__ l10b,
    const float* __restrict__ l20Wih, const float* __restrict__ l20b,
    float* __restrict__ pre,
    const float* __restrict__ fcw2, const float* __restrict__ fcw3,
    float* __restrict__ Wtb)
{
  __shared__ float sb[1440];
  int gb  = blockIdx.x;
  int tid = threadIdx.x;

  if (gb < 36){
    int idx = gb*256 + tid;       // < 9216
    int o = idx >> 10, n = idx & 1023;
    float acc = 0.f;
    for (int p=0;p<192;p++) acc += fcw3[o*192+p]*fcw2[(size_t)p*1024+n];
    Wtb[idx] = acc;
    return;
  }

  // -------- conv + pregate path: 16 rows per block --------
  float* c1s  = sb;          // row*57 + cj   (912)
  float* y4   = sb + 912;    // row*32 + j    (512, b128-aligned)

  int blk = gb - 36;                  // 0..3583
  int branch = (blk >= 1792);
  int lblk = blk - branch*1792;
  int b  = lblk / 14;
  int t0 = (lblk - b*14)*16;
  size_t rbase = ((size_t)(branch*128 + b))*224 + t0;   // global x row
  size_t prow  = (size_t)b*224 + t0;                    // pre row within run

  const float* w1 = branch ? c2w1 : c1w1;
  const float* w2 = branch ? c2w2 : c1w2;
  float b1  = branch ? c2b1[0] : c1b1[0];
  float b2v = branch ? c2b2[0] : c1b2[0];
  const float* wih = branch ? l20Wih : l10Wih;   // (2,48,28)
  const float* bia = branch ? l20b   : l10b;     // (2,48)

  // conv1 stride-4 pad-2 + relu, register-direct: 1 thread per (row, quad)
  if (tid < 224){
    int row  = tid / 14, quad = tid - row*14;
    int cj0  = quad*4;
    int bx   = 4*cj0 - 4;
    const float* xrow = x + (rbase + row)*224;
    float w1r[8];
    #pragma unroll
    for (int kk=0;kk<8;kk++) w1r[kk]=w1[kk];
    float xr[24];
    #pragma unroll
    for (int q=0;q<6;q++){
      int idx = bx + 4*q;
      if (idx >= 0 && idx <= 220){
        float4 v = *(const float4*)(xrow + idx);
        xr[4*q]=v.x; xr[4*q+1]=v.y; xr[4*q+2]=v.z; xr[4*q+3]=v.w;
      } else {
        #pragma unroll
        for (int e=0;e<4;e++){
          int ii = idx+e;
          xr[4*q+e] = (ii>=0 && ii<224) ? xrow[ii] : 0.f;
        }
      }
    }
    #pragma unroll
    for (int e=0;e<4;e++){
      float s = b1;
      #pragma unroll
      for (int kk=0;kk<8;kk++) s += xr[4*e+2+kk]*w1r[kk];
      c1s[row*57 + cj0 + e] = fmaxf(s, 0.f);
    }
  }
  __syncthreads();

  // maxpool(4,2,pad1) + relu + conv3(pad1) + relu
  for (int i = tid; i < 448; i += 256){
    int row = i / 28, j = i - row*28;
    const float* cr = &c1s[row*57];
    float o = b2v;
    #pragma unroll
    for (int pi=0;pi<3;pi++){
      int p = j - 1 + pi;
      float pool = 0.f;
      if (p>=0 && p<28){
        int i0 = 2*p - 1;
        float m = -1e30f;
        #pragma unroll
        for (int q=0;q<4;q++){
          int ii = i0+q;
          if (ii>=0 && ii<56) m = fmaxf(m, cr[ii]);
        }
        pool = fmaxf(m, 0.f);
      }
      o += pool * w2[pi];
    }
    y4[row*32 + j] = fmaxf(o, 0.f);
  }
  __syncthreads();

  // pregate: 192 threads; weights in registers (global, L2-hot)
  if (tid < 192){
    int d   = tid / 96;
    int g96 = tid - d*96;
    int row = g96 % 48;
    int rrg = g96 / 48;
    const float4* wr = (const float4*)(wih + (d*48 + row)*28);  // 112B-aligned
    float4 wv[7];
    #pragma unroll
    for (int q=0;q<7;q++) wv[q] = wr[q];
    float bias = bia[d*48 + row];
    int unit = row % 12, g = row / 12;
    float* prebase = pre + (size_t)(2*branch + d)*(TT*BB*48) + unit*4 + g;
    #pragma unroll
    for (int rq=0; rq<8; rq++){
      int rr = rrg*8 + rq;
      const float4* yv = (const float4*)&y4[rr*32];
      float acc = bias;
      #pragma unroll
      for (int q=0;q<7;q++){
        float4 yq = yv[q];
        acc += yq.x*wv[q].x + yq.y*wv[q].y + yq.z*wv[q].z + yq.w*wv[q].w;
      }
      prebase[(prow + rr)*48] = acc;
    }
  }
}

// ---------------- K3: LSTM scan + light shadow-FC blocks ------------------
// blocks [0,256): lstm single-chain (R11 form).
// phase 0 shadow (layer-1): wpartA-64 (load Wt tile from Wtb, split-K) +
//   BCpart emit.  phase 1 shadow (layer-2): wpartB (Wc reduce) + BC final.
#define LSTM_STEP(P, SS) { \
  float x1=rorN<1>(hv), x2=rorN<2>(hv), x3=rorN<3>(hv), x4=rorN<4>(hv), \
        x5=rorN<5>(hv), x6=rorN<6>(hv), x7=rorN<7>(hv), x8=rorN<8>(hv), \
        x9=rorN<9>(hv), x10=rorN<10>(hv), x11=rorN<11>(hv), x12=rorN<12>(hv), \
        x13=rorN<13>(hv), x14=rorN<14>(hv), x15=rorN<15>(hv); \
  v2f a0 = (P); \
  a0 += w[0]*(v2f){hv,hv};   a0 += w[1]*(v2f){x1,x1};   a0 += w[2]*(v2f){x2,x2};   a0 += w[3]*(v2f){x3,x3}; \
  v2f a1 = w[4]*(v2f){x4,x4};   a1 += w[5]*(v2f){x5,x5};   a1 += w[6]*(v2f){x6,x6};   a1 += w[7]*(v2f){x7,x7}; \
  v2f a2 = w[8]*(v2f){x8,x8};   a2 += w[9]*(v2f){x9,x9};   a2 += w[10]*(v2f){x10,x10}; a2 += w[11]*(v2f){x11,x11}; \
  v2f a3 = w[12]*(v2f){x12,x12}; a3 += w[13]*(v2f){x13,x13}; a3 += w[14]*(v2f){x14,x14}; a3 += w[15]*(v2f){x15,x15}; \
  v2f gg = (a0+a1)+(a2+a3); \
  v2f m  = gg*kmul; \
  v2f e  = { EXP2(m.x), EXP2(m.y) }; \
  e += (v2f){1.f,1.f}; \
  v2f d  = { rcpf(e.x), rcpf(e.y) }; \
  v2f res = ca*d + cb; \
  float p0 = res.x, p1 = res.x; swap32(p0, p1); \
  float q0 = res.y, q1 = res.y; swap32(q0, q1); \
  cst = fmaf(q0, cst, p0*p1); \
  float et = EXP2(cst*2.885390082f); \
  float dt = rcpf(et+1.f); \
  hv = q1*fmaf(-2.f, dt, 1.f); \
  hbuf[SS] = hv; }

#define FLUSH8 { \
  if (doSt){ \
    _Pragma("unroll") \
    for (int q=0;q<8;q++) outP[q*ostep] = hbuf[q]; \
  } \
  outP += 8*ostep; }

__global__ __launch_bounds__(64) __attribute__((amdgpu_waves_per_eu(1,1)))
void lstm_kernel(const float* __restrict__ pre,
    const float* __restrict__ whhA, const float* __restrict__ whhB,
    float* __restrict__ out,
    const float* __restrict__ fcw1, const float* __restrict__ fcb1,
    const float* __restrict__ Wtb,
    float* __restrict__ wpart, float* __restrict__ BCpart,
    const float* __restrict__ fcw3, const float* __restrict__ fcb2,
    const float* __restrict__ fcb3, float* __restrict__ Wc,
    float* __restrict__ BC, int phase)
{
  __shared__ float wt[576];
  int blk  = blockIdx.x;
  int lane = threadIdx.x;

  if (blk >= 256){
    int xb  = blk - 256;
    if (phase == 0){
      // ---- shadow wpartA-64: load Wt tile, split-K over fcw1 ----
      int s   = xb / 84;            // K-chunk 0..15
      int j64 = xb % 84;            // 64-wide j group
      #pragma unroll
      for (int q=0;q<9;q++) wt[q*64+lane] = Wtb[q*1024 + s*64 + lane];
      __syncthreads();
      int j = j64*64 + lane;
      int nbase = s*64;
      float acc[9];
      #pragma unroll
      for (int o=0;o<9;o++) acc[o]=0.f;
      #pragma unroll 4
      for (int n4=0;n4<16;n4++){
        int nb = nbase + n4*4;
        float4 v4;
        v4.x = fcw1[(size_t)(nb  )*5376 + j];
        v4.y = fcw1[(size_t)(nb+1)*5376 + j];
        v4.z = fcw1[(size_t)(nb+2)*5376 + j];
        v4.w = fcw1[(size_t)(nb+3)*5376 + j];
        #pragma unroll
        for (int o=0;o<9;o++){
          float4 w4 = *(const float4*)&wt[o*64 + n4*4];
          acc[o] += v4.x*w4.x + v4.y*w4.y + v4.z*w4.z + v4.w*w4.w;
        }
      }
      #pragma unroll
      for (int o=0;o<9;o++) wpart[((size_t)s*9+o)*5376 + j] = acc[o];
      if (j64 == 0 && lane < 9){
        float bcp = 0.f;
        for (int n=0;n<64;n++) bcp += wt[lane*64+n]*fcb1[nbase+n];
        BCpart[s*9+lane] = bcp;
      }
    } else {
      if (xb < 189){
        // wpartB: Wc = sum_s wpart[s]; 4 elems per lane
        #pragma unroll
        for (int q=0;q<4;q++){
          int idx = xb*256 + q*64 + lane;
          float a = 0.f;
          #pragma unroll
          for (int s=0;s<16;s++) a += wpart[(size_t)s*48384 + idx];
          Wc[idx] = a;
        }
      } else if (lane < 9){
        float acc = fcb3[lane];
        const float* f3 = fcw3 + lane*192;
        for (int p=0;p<192;p++) acc += f3[p]*fcb2[p];
        #pragma unroll
        for (int s=0;s<16;s++) acc += BCpart[s*9+lane];
        BC[lane] = acc;
      }
    }
    return;
  }

  // ---- lstm chain ----
  int r    = blk >> 6;            // run 0..3 (64 blocks per run)
  int br   = r >> 1, dir = r & 1;
  int u    = lane & 15;
  int bh   = (lane >> 4) & 1;
  int rbit = lane >> 5;
  int keff = (u < 12) ? u : 11;
  int b    = (blk & 63)*2 + bh;
  const float* whh = (br ? whhB : whhA) + dir*48*12;

  v2f w[16];
  #pragma unroll
  for (int rr=0; rr<16; rr++){
    int j = (u - rr) & 15;
    bool vld = (j < 12) && (u < 12);
    int uw = (u < 12) ? u : 0;
    int jw = (j < 12) ? j : 0;
    float wa = whh[((rbit?24:0)  + uw)*12 + jw];
    float wb = whh[((rbit?36:12) + uw)*12 + jw];
    w[rr] = (v2f){ vld ? wa : 0.f, vld ? wb : 0.f };
  }
  const v2f kmul = rbit ? (v2f){2.885390082f, -1.442695041f}
                        : (v2f){-1.442695041f, -1.442695041f};
  const v2f ca   = rbit ? (v2f){-2.f, 1.f} : (v2f){1.f, 1.f};
  const v2f cb   = rbit ? (v2f){ 1.f, 0.f} : (v2f){0.f, 0.f};

  const float* preR = pre + (size_t)r*(TT*BB*48) + (size_t)b*(TT*48) + keff*4 + rbit*2;
  const int sstep = dir ? -48 : 48;
  int scb = dir ? 223*48 : 0;

  v2f pcur[8], pnext[8];
  #pragma unroll
  for (int i=0;i<8;i++) pcur[i]  = *(const v2f*)(preR + scb +  i   *sstep);
  #pragma unroll
  for (int i=0;i<8;i++) pnext[i] = *(const v2f*)(preR + scb + (i+8)*sstep);
  int lb = scb + 16*sstep;

  float hv = 0.f, cst = 0.f;
  float hbuf[8];
  const int ostep = dir ? -24 : 24;
  float* outP = out + (size_t)br*(BB*TT*24) + (size_t)b*TT*24 + dir*12 + u
              + (size_t)(dir ? 223 : 0)*24;
  const bool doSt = (rbit==0) && (u < 12);

  for (int c=0;c<14;c++){
    LSTM_STEP(pcur[0],0) LSTM_STEP(pcur[1],1) LSTM_STEP(pcur[2],2) LSTM_STEP(pcur[3],3)
    LSTM_STEP(pcur[4],4) LSTM_STEP(pcur[5],5) LSTM_STEP(pcur[6],6) LSTM_STEP(pcur[7],7)
    FLUSH8
    if (c < 13){
      #pragma unroll
      for (int i=0;i<8;i++) pcur[i] = *(const v2f*)(preR + lb + i*sstep);
      lb += 8*sstep;
    }
    LSTM_STEP(pnext[0],0) LSTM_STEP(pnext[1],1) LSTM_STEP(pnext[2],2) LSTM_STEP(pnext[3],3)
    LSTM_STEP(pnext[4],4) LSTM_STEP(pnext[5],5) LSTM_STEP(pnext[6],6) LSTM_STEP(pnext[7],7)
    FLUSH8
    if (c < 13){
      #pragma unroll
      for (int i=0;i<8;i++) pnext[i] = *(const v2f*)(preR + lb + i*sstep);
      lb += 8*sstep;
    }
  }
}

// -------- K2: layer-2 pre-gate GEMM (pure) -------------------------------
__global__ __launch_bounds__(256) void pregate2_kernel(
    const float* __restrict__ in,
    const float* __restrict__ wihA, const float* __restrict__ biasA,
    const float* __restrict__ wihB, const float* __restrict__ biasB,
    float* __restrict__ pre)
{
  const int D = 24;
  __shared__ float sb[48*24 + 48];
  int gb  = blockIdx.x;
  int tid = threadIdx.x;

  float* wL = sb;
  float* bL = sb + 48*D;
  int r = gb / 1344;
  int lin = (gb % 1344)*256 + tid;
  int br = r>>1, dir = r&1;
  const float* wih  = (br ? wihB  : wihA)  + dir*48*D;
  const float* bias = (br ? biasB : biasA) + dir*48;
  for (int i = tid; i < 48*D; i += 256) wL[i]=wih[i];
  if (tid < 48) bL[tid]=bias[tid];
  __syncthreads();
  int tb = lin/12;  int k = lin - tb*12;   // tb = b*224 + t (batch-major)
  const float* rowp = in + (size_t)br*688128 + (size_t)tb*D;
  float aI=bL[k], aF=bL[12+k], aG=bL[24+k], aO=bL[36+k];
  const float4* rp4 = (const float4*)rowp;
  #pragma unroll
  for (int d4=0; d4<D/4; d4++){
    float4 xv = rp4[d4];
    float4 wI = *(const float4*)&wL[(0*12+k)*D + d4*4];
    float4 wF = *(const float4*)&wL[(1*12+k)*D + d4*4];
    float4 wG = *(const float4*)&wL[(2*12+k)*D + d4*4];
    float4 wO = *(const float4*)&wL[(3*12+k)*D + d4*4];
    aI += xv.x*wI.x + xv.y*wI.y + xv.z*wI.z + xv.w*wI.w;
    aF += xv.x*wF.x + xv.y*wF.y + xv.z*wF.z + xv.w*wF.w;
    aG += xv.x*wG.x + xv.y*wG.y + xv.z*wG.z + xv.w*wG.w;
    aO += xv.x*wO.x + xv.y*wO.y + xv.z*wO.z + xv.w*wO.w;
  }
  float4* o = (float4*)(pre + (size_t)r*(TT*BB*48) + (size_t)tb*48 + k*4);
  *o = make_float4(aI,aF,aG,aO);
}

// ---------------- K6c: out[m][o] = (w1*o1+w2*o2) . Wc[o] + BC[o] ----------
__global__ void final_kernel(const float* __restrict__ o1, const float* __restrict__ o2,
    const float* __restrict__ Wc, const float* __restrict__ BC,
    const float* __restrict__ w1p, const float* __restrict__ w2p,
    float* __restrict__ out)
{
  int wid  = blockIdx.x*4 + (threadIdx.x>>6);
  int lane = threadIdx.x & 63;
  if (wid >= 128*9) return;
  int m = wid / 9, o = wid - m*9;
  float w1 = w1p[0], w2 = w2p[0];
  const float* r1 = o1 + (size_t)m*5376;
  const float* r2 = o2 + (size_t)m*5376;
  const float* wc = Wc + (size_t)o*5376;
  float acc = 0.f;
  for (int i=lane;i<5376;i+=64){
    acc += (w1*r1[i] + w2*r2[i]) * wc[i];
  }
  #pragma unroll
  for (int off=32;off;off>>=1) acc += __shfl_down(acc, off);
  if (lane==0) out[m*9+o] = acc + BC[o];
}

extern "C" void kernel_launch(void* const* d_in, const int* in_sizes, int n_in,
                              void* d_out, int out_size, void* d_ws, size_t ws_size,
                              hipStream_t stream) {
  (void)in_sizes; (void)n_in; (void)out_size; (void)ws_size;
  const float* x    = (const float*)d_in[0];
  const float* c1w1 = (const float*)d_in[1];
  const float* c1b1 = (const float*)d_in[2];
  const float* c1w2 = (const float*)d_in[3];
  const float* c1b2 = (const float*)d_in[4];
  const float* c2w1 = (const float*)d_in[5];
  const float* c2b1 = (const float*)d_in[6];
  const float* c2w2 = (const float*)d_in[7];
  const float* c2b2 = (const float*)d_in[8];
  const float* l10Wih = (const float*)d_in[9];
  const float* l10Whh = (const float*)d_in[10];
  const float* l10b   = (const float*)d_in[11];
  const float* l11Wih = (const float*)d_in[12];
  const float* l11Whh = (const float*)d_in[13];
  const float* l11b   = (const float*)d_in[14];
  const float* l20Wih = (const float*)d_in[15];
  const float* l20Whh = (const float*)d_in[16];
  const float* l20b   = (const float*)d_in[17];
  const float* l21Wih = (const float*)d_in[18];
  const float* l21Whh = (const float*)d_in[19];
  const float* l21b   = (const float*)d_in[20];
  const float* fcw1 = (const float*)d_in[21];
  const float* fcb1 = (const float*)d_in[22];
  const float* fcw2 = (const float*)d_in[23];
  const float* fcb2 = (const float*)d_in[24];
  const float* fcw3 = (const float*)d_in[25];
  const float* fcb3 = (const float*)d_in[26];
  const float* w1   = (const float*)d_in[27];
  const float* w2   = (const float*)d_in[28];
  float* out = (float*)d_out;

  float* ws  = (float*)d_ws;
  float* wpart = ws;                      // 774144
  float* pre  = ws  + 2*802816;           // 4 * 1376256
  float* ol0  = pre + 4*1376256;          // 2 * 688128
  float* ol1  = ol0 + 2*688128;           // 2 * 688128
  float* Wc   = ol1 + 2*688128;           // 48384
  float* BC   = Wc  + 48384;              // 9
  float* BCpart = BC + 9;                 // 144
  float* Wtb  = BCpart + 144;             // 9216

  convpre_kernel<<<3620,256,0,stream>>>(x, c1w1,c1b1,c1w2,c1b2, c2w1,c2b1,c2w2,c2b2,
      l10Wih, l10b, l20Wih, l20b, pre, fcw2, fcw3, Wtb);
  lstm_kernel<<<1600,64,0,stream>>>(pre, l10Whh, l20Whh, ol0,
      fcw1, fcb1, Wtb, wpart, BCpart, fcw3, fcb2, fcb3, Wc, BC, 0);
  pregate2_kernel<<<5376,256,0,stream>>>(ol0, l11Wih, l11b, l21Wih, l21b, pre);
  lstm_kernel<<<446,64,0,stream>>>(pre, l11Whh, l21Whh, ol1,
      fcw1, fcb1, Wtb, wpart, BCpart, fcw3, fcb2, fcb3, Wc, BC, 1);
  final_kernel<<<288,256,0,stream>>>(ol1, ol1+688128, Wc, BC, w1, w2, out);
}

// Round 24
// 158.503 us; speedup vs baseline: 1.2746x; 1.0320x over previous
//
#include <hip/hip_runtime.h>

#define BB 128
#define TT 224
#define LL 224

typedef float v2f __attribute__((ext_vector_type(2)));

__device__ __forceinline__ float rcpf(float x){ return __builtin_amdgcn_rcpf(x); }

#if __has_builtin(__builtin_amdgcn_exp2f)
#define EXP2(x) __builtin_amdgcn_exp2f(x)
#else
#define EXP2(x) __expf((x)*0.6931471805599453f)
#endif

// DPP row rotate-right by N: dst[k] = src[(k-N)&15] within each 16-lane row
template<int N>
__device__ __forceinline__ float rorN(float x){
  int xi = __builtin_bit_cast(int, x);
  xi = __builtin_amdgcn_update_dpp(xi, xi, 0x120 + N, 0xf, 0xf, false);
  return __builtin_bit_cast(float, xi);
}

// v_permlane32_swap_b32: with a==b==x -> a'=low-half bcast, b'=high-half bcast
__device__ __forceinline__ void swap32(float& a, float& b){
  asm volatile("s_nop 1\n\tv_permlane32_swap_b32 %0, %1\n\ts_nop 1"
               : "+v"(a), "+v"(b));
}

// ---- K1: conv chain + layer-1 pre-gate + Wtb precompute (R21 form) -------
__global__ __launch_bounds__(256) void convpre_kernel(const float* __restrict__ x,
    const float* __restrict__ c1w1, const float* __restrict__ c1b1,
    const float* __restrict__ c1w2, const float* __restrict__ c1b2,
    const float* __restrict__ c2w1, const float* __restrict__ c2b1,
    const float* __restrict__ c2w2, const float* __restrict__ c2b2,
    const float* __restrict__ l10Wih, const float* __restrict__ l10b,
    const float* __restrict__ l20Wih, const float* __restrict__ l20b,
    float* __restrict__ pre,
    const float* __restrict__ fcw2, const float* __restrict__ fcw3,
    float* __restrict__ Wtb)
{
  __shared__ float sb[1440];
  int gb  = blockIdx.x;
  int tid = threadIdx.x;

  if (gb < 36){
    int idx = gb*256 + tid;       // < 9216
    int o = idx >> 10, n = idx & 1023;
    float acc = 0.f;
    for (int p=0;p<192;p++) acc += fcw3[o*192+p]*fcw2[(size_t)p*1024+n];
    Wtb[idx] = acc;
    return;
  }

  float* c1s  = sb;          // row*57 + cj   (912)
  float* y4   = sb + 912;    // row*32 + j    (512, b128-aligned)

  int blk = gb - 36;                  // 0..3583
  int branch = (blk >= 1792);
  int lblk = blk - branch*1792;
  int b  = lblk / 14;
  int t0 = (lblk - b*14)*16;
  size_t rbase = ((size_t)(branch*128 + b))*224 + t0;
  size_t prow  = (size_t)b*224 + t0;

  const float* w1 = branch ? c2w1 : c1w1;
  const float* w2 = branch ? c2w2 : c1w2;
  float b1  = branch ? c2b1[0] : c1b1[0];
  float b2v = branch ? c2b2[0] : c1b2[0];
  const float* wih = branch ? l20Wih : l10Wih;   // (2,48,28)
  const float* bia = branch ? l20b   : l10b;     // (2,48)

  if (tid < 224){
    int row  = tid / 14, quad = tid - row*14;
    int cj0  = quad*4;
    int bx   = 4*cj0 - 4;
    const float* xrow = x + (rbase + row)*224;
    float w1r[8];
    #pragma unroll
    for (int kk=0;kk<8;kk++) w1r[kk]=w1[kk];
    float xr[24];
    #pragma unroll
    for (int q=0;q<6;q++){
      int idx = bx + 4*q;
      if (idx >= 0 && idx <= 220){
        float4 v = *(const float4*)(xrow + idx);
        xr[4*q]=v.x; xr[4*q+1]=v.y; xr[4*q+2]=v.z; xr[4*q+3]=v.w;
      } else {
        #pragma unroll
        for (int e=0;e<4;e++){
          int ii = idx+e;
          xr[4*q+e] = (ii>=0 && ii<224) ? xrow[ii] : 0.f;
        }
      }
    }
    #pragma unroll
    for (int e=0;e<4;e++){
      float s = b1;
      #pragma unroll
      for (int kk=0;kk<8;kk++) s += xr[4*e+2+kk]*w1r[kk];
      c1s[row*57 + cj0 + e] = fmaxf(s, 0.f);
    }
  }
  __syncthreads();

  for (int i = tid; i < 448; i += 256){
    int row = i / 28, j = i - row*28;
    const float* cr = &c1s[row*57];
    float o = b2v;
    #pragma unroll
    for (int pi=0;pi<3;pi++){
      int p = j - 1 + pi;
      float pool = 0.f;
      if (p>=0 && p<28){
        int i0 = 2*p - 1;
        float m = -1e30f;
        #pragma unroll
        for (int q=0;q<4;q++){
          int ii = i0+q;
          if (ii>=0 && ii<56) m = fmaxf(m, cr[ii]);
        }
        pool = fmaxf(m, 0.f);
      }
      o += pool * w2[pi];
    }
    y4[row*32 + j] = fmaxf(o, 0.f);
  }
  __syncthreads();

  if (tid < 192){
    int d   = tid / 96;
    int g96 = tid - d*96;
    int row = g96 % 48;
    int rrg = g96 / 48;
    const float4* wr = (const float4*)(wih + (d*48 + row)*28);
    float4 wv[7];
    #pragma unroll
    for (int q=0;q<7;q++) wv[q] = wr[q];
    float bias = bia[d*48 + row];
    int unit = row % 12, g = row / 12;
    float* prebase = pre + (size_t)(2*branch + d)*(TT*BB*48) + unit*4 + g;
    #pragma unroll
    for (int rq=0; rq<8; rq++){
      int rr = rrg*8 + rq;
      const float4* yv = (const float4*)&y4[rr*32];
      float acc = bias;
      #pragma unroll
      for (int q=0;q<7;q++){
        float4 yq = yv[q];
        acc += yq.x*wv[q].x + yq.y*wv[q].y + yq.z*wv[q].z + yq.w*wv[q].w;
      }
      prebase[(prow + rr)*48] = acc;
    }
  }
}

// ---------------- shared LSTM step macro ----------------------------------
#define LSTM_STEP(P, SS) { \
  float x1=rorN<1>(hv), x2=rorN<2>(hv), x3=rorN<3>(hv), x4=rorN<4>(hv), \
        x5=rorN<5>(hv), x6=rorN<6>(hv), x7=rorN<7>(hv), x8=rorN<8>(hv), \
        x9=rorN<9>(hv), x10=rorN<10>(hv), x11=rorN<11>(hv), x12=rorN<12>(hv), \
        x13=rorN<13>(hv), x14=rorN<14>(hv), x15=rorN<15>(hv); \
  v2f a0 = (P); \
  a0 += w[0]*(v2f){hv,hv};   a0 += w[1]*(v2f){x1,x1};   a0 += w[2]*(v2f){x2,x2};   a0 += w[3]*(v2f){x3,x3}; \
  v2f a1 = w[4]*(v2f){x4,x4};   a1 += w[5]*(v2f){x5,x5};   a1 += w[6]*(v2f){x6,x6};   a1 += w[7]*(v2f){x7,x7}; \
  v2f a2 = w[8]*(v2f){x8,x8};   a2 += w[9]*(v2f){x9,x9};   a2 += w[10]*(v2f){x10,x10}; a2 += w[11]*(v2f){x11,x11}; \
  v2f a3 = w[12]*(v2f){x12,x12}; a3 += w[13]*(v2f){x13,x13}; a3 += w[14]*(v2f){x14,x14}; a3 += w[15]*(v2f){x15,x15}; \
  v2f gg = (a0+a1)+(a2+a3); \
  v2f m  = gg*kmul; \
  v2f e  = { EXP2(m.x), EXP2(m.y) }; \
  e += (v2f){1.f,1.f}; \
  v2f d  = { rcpf(e.x), rcpf(e.y) }; \
  v2f res = ca*d + cb; \
  float p0 = res.x, p1 = res.x; swap32(p0, p1); \
  float q0 = res.y, q1 = res.y; swap32(q0, q1); \
  cst = fmaf(q0, cst, p0*p1); \
  float et = EXP2(cst*2.885390082f); \
  float dt = rcpf(et+1.f); \
  hv = q1*fmaf(-2.f, dt, 1.f); \
  hbuf[SS] = hv; }

#define FLUSH8 { \
  if (doSt){ \
    _Pragma("unroll") \
    for (int q=0;q<8;q++) outP[q*ostep] = hbuf[q]; \
  } \
  outP += 8*ostep; }

// ---------------- K3a: layer-1 LSTM + shadow wpartA -----------------------
__global__ __launch_bounds__(64) __attribute__((amdgpu_waves_per_eu(1,1)))
void lstm_kernel(const float* __restrict__ pre,
    const float* __restrict__ whhA, const float* __restrict__ whhB,
    float* __restrict__ out,
    const float* __restrict__ fcw1, const float* __restrict__ fcb1,
    const float* __restrict__ Wtb,
    float* __restrict__ wpart, float* __restrict__ BCpart)
{
  __shared__ float wt[576];
  int blk  = blockIdx.x;
  int lane = threadIdx.x;

  if (blk >= 256){
    int xb  = blk - 256;          // 0..1343
    int s   = xb / 84;
    int j64 = xb % 84;
    #pragma unroll
    for (int q=0;q<9;q++) wt[q*64+lane] = Wtb[q*1024 + s*64 + lane];
    __syncthreads();
    int j = j64*64 + lane;
    int nbase = s*64;
    float acc[9];
    #pragma unroll
    for (int o=0;o<9;o++) acc[o]=0.f;
    #pragma unroll 4
    for (int n4=0;n4<16;n4++){
      int nb = nbase + n4*4;
      float4 v4;
      v4.x = fcw1[(size_t)(nb  )*5376 + j];
      v4.y = fcw1[(size_t)(nb+1)*5376 + j];
      v4.z = fcw1[(size_t)(nb+2)*5376 + j];
      v4.w = fcw1[(size_t)(nb+3)*5376 + j];
      #pragma unroll
      for (int o=0;o<9;o++){
        float4 w4 = *(const float4*)&wt[o*64 + n4*4];
        acc[o] += v4.x*w4.x + v4.y*w4.y + v4.z*w4.z + v4.w*w4.w;
      }
    }
    #pragma unroll
    for (int o=0;o<9;o++) wpart[((size_t)s*9+o)*5376 + j] = acc[o];
    if (j64 == 0 && lane < 9){
      float bcp = 0.f;
      for (int n=0;n<64;n++) bcp += wt[lane*64+n]*fcb1[nbase+n];
      BCpart[s*9+lane] = bcp;
    }
    return;
  }

  int r    = blk >> 6;
  int br   = r >> 1, dir = r & 1;
  int u    = lane & 15;
  int bh   = (lane >> 4) & 1;
  int rbit = lane >> 5;
  int keff = (u < 12) ? u : 11;
  int b    = (blk & 63)*2 + bh;
  const float* whh = (br ? whhB : whhA) + dir*48*12;

  v2f w[16];
  #pragma unroll
  for (int rr=0; rr<16; rr++){
    int j = (u - rr) & 15;
    bool vld = (j < 12) && (u < 12);
    int uw = (u < 12) ? u : 0;
    int jw = (j < 12) ? j : 0;
    float wa = whh[((rbit?24:0)  + uw)*12 + jw];
    float wb = whh[((rbit?36:12) + uw)*12 + jw];
    w[rr] = (v2f){ vld ? wa : 0.f, vld ? wb : 0.f };
  }
  const v2f kmul = rbit ? (v2f){2.885390082f, -1.442695041f}
                        : (v2f){-1.442695041f, -1.442695041f};
  const v2f ca   = rbit ? (v2f){-2.f, 1.f} : (v2f){1.f, 1.f};
  const v2f cb   = rbit ? (v2f){ 1.f, 0.f} : (v2f){0.f, 0.f};

  const float* preR = pre + (size_t)r*(TT*BB*48) + (size_t)b*(TT*48) + keff*4 + rbit*2;
  const int sstep = dir ? -48 : 48;
  int scb = dir ? 223*48 : 0;

  v2f pcur[8], pnext[8];
  #pragma unroll
  for (int i=0;i<8;i++) pcur[i]  = *(const v2f*)(preR + scb +  i   *sstep);
  #pragma unroll
  for (int i=0;i<8;i++) pnext[i] = *(const v2f*)(preR + scb + (i+8)*sstep);
  int lb = scb + 16*sstep;

  float hv = 0.f, cst = 0.f;
  float hbuf[8];
  const int ostep = dir ? -24 : 24;
  float* outP = out + (size_t)br*(BB*TT*24) + (size_t)b*TT*24 + dir*12 + u
              + (size_t)(dir ? 223 : 0)*24;
  const bool doSt = (rbit==0) && (u < 12);

  for (int c=0;c<14;c++){
    LSTM_STEP(pcur[0],0) LSTM_STEP(pcur[1],1) LSTM_STEP(pcur[2],2) LSTM_STEP(pcur[3],3)
    LSTM_STEP(pcur[4],4) LSTM_STEP(pcur[5],5) LSTM_STEP(pcur[6],6) LSTM_STEP(pcur[7],7)
    FLUSH8
    if (c < 13){
      #pragma unroll
      for (int i=0;i<8;i++) pcur[i] = *(const v2f*)(preR + lb + i*sstep);
      lb += 8*sstep;
    }
    LSTM_STEP(pnext[0],0) LSTM_STEP(pnext[1],1) LSTM_STEP(pnext[2],2) LSTM_STEP(pnext[3],3)
    LSTM_STEP(pnext[4],4) LSTM_STEP(pnext[5],5) LSTM_STEP(pnext[6],6) LSTM_STEP(pnext[7],7)
    FLUSH8
    if (c < 13){
      #pragma unroll
      for (int i=0;i<8;i++) pnext[i] = *(const v2f*)(preR + lb + i*sstep);
      lb += 8*sstep;
    }
  }
}

// ---- K3b: layer-2 FUSED: wave0 = lstm consumer; waves1-3 = pregate -------
// producers (ol0 -> LDS gate buffer, in consumption order, flag per group).
__global__ __launch_bounds__(256) __attribute__((amdgpu_waves_per_eu(1,1)))
void lstm2_fused_kernel(const float* __restrict__ ol0,
    const float* __restrict__ whhA, const float* __restrict__ whhB,
    const float* __restrict__ wihA, const float* __restrict__ biasA,
    const float* __restrict__ wihB, const float* __restrict__ biasB,
    float* __restrict__ out)
{
  __shared__ float lpre[2*224*48];     // 86016 B
  __shared__ int prog[4];
  int tid  = threadIdx.x;
  int blk  = blockIdx.x;
  int r    = blk >> 6;
  int br   = r >> 1, dir = r & 1;
  int b0   = (blk & 63)*2;

  if (tid < 4) ((volatile int*)prog)[tid] = 0;
  __syncthreads();

  if (tid >= 64){
    // ---------------- producers ----------------
    int p    = tid - 64;          // 0..191
    int wv   = p >> 6;            // 0..2
    int e    = p % 96;
    int th   = p / 96;            // 0/1: s-half
    int bb   = e / 48;
    int gate = e % 48;
    const float* wih2 = (br ? wihB : wihA) + (dir*48 + gate)*24;
    float4 wq[6];
    #pragma unroll
    for (int q=0;q<6;q++) wq[q] = ((const float4*)wih2)[q];
    float bias = (br ? biasB : biasA)[dir*48 + gate];
    int unit = gate % 12, gg = gate / 12;
    const float* olrow = ol0 + (size_t)br*(BB*TT*24) + (size_t)(b0+bb)*TT*24;
    float* lrow = lpre + bb*(224*48) + unit*4 + gg;
    volatile int* pv = prog;

    for (int g=0; g<28; g++){
      #pragma unroll
      for (int si=0; si<4; si++){
        int step = g*8 + th*4 + si;
        int t = dir ? 223 - step : step;
        const float4* xr = (const float4*)(olrow + t*24);
        float a = bias;
        #pragma unroll
        for (int q=0;q<6;q++){
          float4 xq = xr[q];
          a += xq.x*wq[q].x + xq.y*wq[q].y + xq.z*wq[q].z + xq.w*wq[q].w;
        }
        lrow[t*48] = a;
      }
      asm volatile("s_waitcnt lgkmcnt(0) vmcnt(0)" ::: "memory");
      if ((p & 63) == 0) pv[wv] = g+1;
    }
    return;
  }

  // ---------------- consumer (lstm chain) ----------------
  int lane = tid;
  int u    = lane & 15;
  int bh   = (lane >> 4) & 1;
  int rbit = lane >> 5;
  int keff = (u < 12) ? u : 11;
  int b    = b0 + bh;
  const float* whh = (br ? whhB : whhA) + dir*48*12;

  v2f w[16];
  #pragma unroll
  for (int rr=0; rr<16; rr++){
    int j = (u - rr) & 15;
    bool vld = (j < 12) && (u < 12);
    int uw = (u < 12) ? u : 0;
    int jw = (j < 12) ? j : 0;
    float wa = whh[((rbit?24:0)  + uw)*12 + jw];
    float wb = whh[((rbit?36:12) + uw)*12 + jw];
    w[rr] = (v2f){ vld ? wa : 0.f, vld ? wb : 0.f };
  }
  const v2f kmul = rbit ? (v2f){2.885390082f, -1.442695041f}
                        : (v2f){-1.442695041f, -1.442695041f};
  const v2f ca   = rbit ? (v2f){-2.f, 1.f} : (v2f){1.f, 1.f};
  const v2f cb   = rbit ? (v2f){ 1.f, 0.f} : (v2f){0.f, 0.f};

  float* preR = lpre + bh*(224*48) + keff*4 + rbit*2;
  const int sstep = dir ? -48 : 48;
  int scb = dir ? 223*48 : 0;
  volatile int* pv = prog;

#define WAITG(NEED) { int nd_ = (NEED); \
  while (pv[0] < nd_ || pv[1] < nd_ || pv[2] < nd_) __builtin_amdgcn_s_sleep(2); \
  asm volatile("" ::: "memory"); }

  WAITG(2)
  v2f pcur[8], pnext[8];
  #pragma unroll
  for (int i=0;i<8;i++) pcur[i]  = *(const v2f*)(preR + scb +  i   *sstep);
  #pragma unroll
  for (int i=0;i<8;i++) pnext[i] = *(const v2f*)(preR + scb + (i+8)*sstep);
  int lb = scb + 16*sstep;

  float hv = 0.f, cst = 0.f;
  float hbuf[8];
  const int ostep = dir ? -24 : 24;
  float* outP = out + (size_t)br*(BB*TT*24) + (size_t)b*TT*24 + dir*12 + u
              + (size_t)(dir ? 223 : 0)*24;
  const bool doSt = (rbit==0) && (u < 12);

  for (int c=0;c<14;c++){
    LSTM_STEP(pcur[0],0) LSTM_STEP(pcur[1],1) LSTM_STEP(pcur[2],2) LSTM_STEP(pcur[3],3)
    LSTM_STEP(pcur[4],4) LSTM_STEP(pcur[5],5) LSTM_STEP(pcur[6],6) LSTM_STEP(pcur[7],7)
    FLUSH8
    if (c < 13){
      WAITG(2*c+3)
      #pragma unroll
      for (int i=0;i<8;i++) pcur[i] = *(const v2f*)(preR + lb + i*sstep);
      lb += 8*sstep;
    }
    LSTM_STEP(pnext[0],0) LSTM_STEP(pnext[1],1) LSTM_STEP(pnext[2],2) LSTM_STEP(pnext[3],3)
    LSTM_STEP(pnext[4],4) LSTM_STEP(pnext[5],5) LSTM_STEP(pnext[6],6) LSTM_STEP(pnext[7],7)
    FLUSH8
    if (c < 13){
      WAITG(2*c+4)
      #pragma unroll
      for (int i=0;i<8;i++) pnext[i] = *(const v2f*)(preR + lb + i*sstep);
      lb += 8*sstep;
    }
  }
#undef WAITG
}

// -------- K4: wpartB (Wc reduce) + BC finalize ----------------------------
__global__ __launch_bounds__(256) void wpartB_kernel(
    const float* __restrict__ wpart, float* __restrict__ Wc,
    const float* __restrict__ fcw3, const float* __restrict__ fcb2,
    const float* __restrict__ fcb3, const float* __restrict__ BCpart,
    float* __restrict__ BC)
{
  int gb  = blockIdx.x;
  int tid = threadIdx.x;
  if (gb < 189){
    int idx = gb*256 + tid;   // 189*256 = 48384
    float a = 0.f;
    #pragma unroll
    for (int s=0;s<16;s++) a += wpart[(size_t)s*48384 + idx];
    Wc[idx] = a;
  } else if (tid < 9){
    float acc = fcb3[tid];
    const float* f3 = fcw3 + tid*192;
    for (int p=0;p<192;p++) acc += f3[p]*fcb2[p];
    #pragma unroll
    for (int s=0;s<16;s++) acc += BCpart[s*9+tid];
    BC[tid] = acc;
  }
}

// ---------------- K6c: out[m][o] = (w1*o1+w2*o2) . Wc[o] + BC[o] ----------
__global__ void final_kernel(const float* __restrict__ o1, const float* __restrict__ o2,
    const float* __restrict__ Wc, const float* __restrict__ BC,
    const float* __restrict__ w1p, const float* __restrict__ w2p,
    float* __restrict__ out)
{
  int wid  = blockIdx.x*4 + (threadIdx.x>>6);
  int lane = threadIdx.x & 63;
  if (wid >= 128*9) return;
  int m = wid / 9, o = wid - m*9;
  float w1 = w1p[0], w2 = w2p[0];
  const float* r1 = o1 + (size_t)m*5376;
  const float* r2 = o2 + (size_t)m*5376;
  const float* wc = Wc + (size_t)o*5376;
  float acc = 0.f;
  for (int i=lane;i<5376;i+=64){
    acc += (w1*r1[i] + w2*r2[i]) * wc[i];
  }
  #pragma unroll
  for (int off=32;off;off>>=1) acc += __shfl_down(acc, off);
  if (lane==0) out[m*9+o] = acc + BC[o];
}

extern "C" void kernel_launch(void* const* d_in, const int* in_sizes, int n_in,
                              void* d_out, int out_size, void* d_ws, size_t ws_size,
                              hipStream_t stream) {
  (void)in_sizes; (void)n_in; (void)out_size; (void)ws_size;
  const float* x    = (const float*)d_in[0];
  const float* c1w1 = (const float*)d_in[1];
  const float* c1b1 = (const float*)d_in[2];
  const float* c1w2 = (const float*)d_in[3];
  const float* c1b2 = (const float*)d_in[4];
  const float* c2w1 = (const float*)d_in[5];
  const float* c2b1 = (const float*)d_in[6];
  const float* c2w2 = (const float*)d_in[7];
  const float* c2b2 = (const float*)d_in[8];
  const float* l10Wih = (const float*)d_in[9];
  const float* l10Whh = (const float*)d_in[10];
  const float* l10b   = (const float*)d_in[11];
  const float* l11Wih = (const float*)d_in[12];
  const float* l11Whh = (const float*)d_in[13];
  const float* l11b   = (const float*)d_in[14];
  const float* l20Wih = (const float*)d_in[15];
  const float* l20Whh = (const float*)d_in[16];
  const float* l20b   = (const float*)d_in[17];
  const float* l21Wih = (const float*)d_in[18];
  const float* l21Whh = (const float*)d_in[19];
  const float* l21b   = (const float*)d_in[20];
  const float* fcw1 = (const float*)d_in[21];
  const float* fcb1 = (const float*)d_in[22];
  const float* fcw2 = (const float*)d_in[23];
  const float* fcb2 = (const float*)d_in[24];
  const float* fcw3 = (const float*)d_in[25];
  const float* fcb3 = (const float*)d_in[26];
  const float* w1   = (const float*)d_in[27];
  const float* w2   = (const float*)d_in[28];
  float* out = (float*)d_out;

  float* ws  = (float*)d_ws;
  float* wpart = ws;                      // 774144
  float* pre  = ws  + 2*802816;           // 4 * 1376256
  float* ol0  = pre + 4*1376256;          // 2 * 688128
  float* ol1  = ol0 + 2*688128;           // 2 * 688128
  float* Wc   = ol1 + 2*688128;           // 48384
  float* BC   = Wc  + 48384;              // 9
  float* BCpart = BC + 9;                 // 144
  float* Wtb  = BCpart + 144;             // 9216

  convpre_kernel<<<3620,256,0,stream>>>(x, c1w1,c1b1,c1w2,c1b2, c2w1,c2b1,c2w2,c2b2,
      l10Wih, l10b, l20Wih, l20b, pre, fcw2, fcw3, Wtb);
  lstm_kernel<<<1600,64,0,stream>>>(pre, l10Whh, l20Whh, ol0,
      fcw1, fcb1, Wtb, wpart, BCpart);
  wpartB_kernel<<<190,256,0,stream>>>(wpart, Wc, fcw3, fcb2, fcb3, BCpart, BC);
  lstm2_fused_kernel<<<256,256,0,stream>>>(ol0, l11Whh, l21Whh,
      l11Wih, l11b, l21Wih, l21b, ol1);
  final_kernel<<<288,256,0,stream>>>(ol1, ol1+688128, Wc, BC, w1, w2, out);
}